// Round 11
// baseline (419.981 us; speedup 1.0000x reference)
//
#include <hip/hip_runtime.h>

// APMLSparse: B=4, N=M=4096, D=3.
// loss = sum_rows sum_{kept j} p_ij * d_ij, p = softmax_j(-d_i),
// kept = descending-p prefix until cumulative mass >= P_MIN = 0.8.
//
// R18: histogram threshold-finder. Validated model: dur = issue / util(occ),
// util saturates ~110 at >=4 waves/SIMD (knee). R17 proved -20% issue is
// real but pd regs broke occupancy. This version cuts issue WITHOUT regs:
// bin = (float_bits(p) >> 20) - 0x2F8 is MONOTONE in p; a per-wave
// 256-bin mass histogram (LDS atomicAdd during setup) + one suffix-scan
// replaces warm-start + pmax + A0 + A probes (~820 slots, 7 serial
// rounds) with ~450 slots, 0 rounds. Bracket bin edges are bit-exact
// floats; Gl/Gh from bin suffix sums (atomic-order last-bit wiggle --
// tolerance absorbs far larger reassociations, R12-R17). Band = one bin;
// overflow -> classic probe-refine fallback (rare), then recompact.
// B/C1/C2/D/epilogue byte-identical to R10/R14. Registers unchanged.

#define MCOLS 4096
#define KPT   64            // 4096 / 64 lanes
#define WPB   4             // waves per block
#define P_MIN 0.8f
#define BINBASE 0x2F8       // (bits>>20)-BINBASE maps p in (0,1) to [0,255]

// ---- DPP wave64 reductions (old=0 => disabled/out-of-range lanes add 0) ----
template <int CTRL, int RM, int BM, bool BC>
__device__ __forceinline__ float dpp_mov0(float x) {
    return __int_as_float(__builtin_amdgcn_update_dpp(
        0, __float_as_int(x), CTRL, RM, BM, BC));
}
__device__ __forceinline__ float dppSum(float v) {
    v += dpp_mov0<0x111, 0xF, 0xF, true >(v);   // row_shr:1
    v += dpp_mov0<0x112, 0xF, 0xF, true >(v);   // row_shr:2
    v += dpp_mov0<0x114, 0xF, 0xF, true >(v);   // row_shr:4
    v += dpp_mov0<0x118, 0xF, 0xF, true >(v);   // row_shr:8
    v += dpp_mov0<0x142, 0xA, 0xF, false>(v);   // row_bcast15 -> rows 1,3
    v += dpp_mov0<0x143, 0xC, 0xF, false>(v);   // row_bcast31 -> rows 2,3
    return __int_as_float(__builtin_amdgcn_readlane(__float_as_int(v), 63));
}
__device__ __forceinline__ float dppPrefixIncl(float v) {   // per-lane incl. prefix
    v += dpp_mov0<0x111, 0xF, 0xF, true >(v);
    v += dpp_mov0<0x112, 0xF, 0xF, true >(v);
    v += dpp_mov0<0x114, 0xF, 0xF, true >(v);
    v += dpp_mov0<0x118, 0xF, 0xF, true >(v);
    v += dpp_mov0<0x142, 0xA, 0xF, false>(v);
    v += dpp_mov0<0x143, 0xC, 0xF, false>(v);
    return v;
}
__device__ __forceinline__ float dppMax(float v) {   // nonneg inputs only
    v = fmaxf(v, dpp_mov0<0x111, 0xF, 0xF, true >(v));
    v = fmaxf(v, dpp_mov0<0x112, 0xF, 0xF, true >(v));
    v = fmaxf(v, dpp_mov0<0x114, 0xF, 0xF, true >(v));
    v = fmaxf(v, dpp_mov0<0x118, 0xF, 0xF, true >(v));
    v = fmaxf(v, dpp_mov0<0x142, 0xA, 0xF, false>(v));
    v = fmaxf(v, dpp_mov0<0x143, 0xC, 0xF, false>(v));
    return __int_as_float(__builtin_amdgcn_readlane(__float_as_int(v), 63));
}

__global__ __launch_bounds__(WPB * 64) void apml_row_wave(
        const float* __restrict__ x, const float* __restrict__ y,
        float* __restrict__ partial, float* __restrict__ out) {
    __shared__ __align__(16) float hist[WPB * 256];    // per-wave bin masses
    __shared__ __align__(16) float scomp[WPB * 256];
    __shared__ float wacc[WPB];

    const int tid  = threadIdx.x;
    const int wid  = tid >> 6;
    const int lane = tid & 63;
    const int row  = blockIdx.x * WPB + wid;
    const int b    = row >> 12;                 // row / 4096
    const int hb   = wid * 256;

    const float x0 = x[row * 3 + 0];
    const float x1 = x[row * 3 + 1];
    const float x2 = x[row * 3 + 2];
    const float* yb = y + (size_t)b * MCOLS * 3;

    // zero own wave's histogram (wave-private; no barrier needed)
    #pragma unroll
    for (int q = 0; q < 4; ++q) hist[hb + q * 64 + lane] = 0.0f;
    __builtin_amdgcn_s_waitcnt(0);

    // ---- setup: p = exp(-d) in regs; Z (serial, value-critical order);
    //      mass histogram over float-bit bins (monotone in p) ----
    float p[KPT];
    float zl = 0.0f;
    #pragma unroll
    for (int k = 0; k < KPT; ++k) {
        const int j = k * 64 + lane;
        const float y0 = yb[j * 3 + 0];
        const float y1 = yb[j * 3 + 1];
        const float y2 = yb[j * 3 + 2];
        const float dx = x0 - y0, dy = x1 - y1, dz = x2 - y2;
        const float sq = fmaxf(dx * dx + dy * dy + dz * dz, 1e-12f); // EPS^2
        const float pk = __expf(-sqrtf(sq));
        p[k] = pk;
        zl  += pk;
        int bin = (int)(__float_as_uint(pk) >> 20) - BINBASE;
        bin = bin < 0 ? 0 : bin;               // clamp ultra-small p to bin 0
        atomicAdd(&hist[hb + bin], pk);        // ds_add_f32, fire-and-forget
    }
    __builtin_amdgcn_s_waitcnt(0);
    const float Z      = dppSum(zl);
    const float target = P_MIN * Z;

    // ---- suffix-scan of bins -> exact bracket (replaces warm/A0/A) ----
    // lane owns bins 4*lane .. 4*lane+3; S(b) = mass of bins >= b.
    const float4 mm = *reinterpret_cast<const float4*>(&hist[hb + 4 * lane]);
    const float tl  = (mm.x + mm.y) + (mm.z + mm.w);
    const float pfx = dppPrefixIncl(tl);       // inclusive prefix over lanes
    const float total = __int_as_float(
        __builtin_amdgcn_readlane(__float_as_int(pfx), 63));
    const float Tnx = total - pfx;             // mass strictly above my bins
    const float S3 = mm.w + Tnx;
    const float S2 = mm.z + S3;
    const float S1 = mm.y + S2;
    const float S0 = mm.x + S1;
    int cand = -1;                             // largest bin with S >= target
    if (S0 >= target) cand = 4 * lane + 0;
    if (S1 >= target) cand = 4 * lane + 1;
    if (S2 >= target) cand = 4 * lane + 2;
    if (S3 >= target) cand = 4 * lane + 3;
    const int binsel = (int)dppMax((float)(cand + 1)) - 1;  // >=0 (S(0)=total)

    // publish S values, fetch Gl/Gh at the selected boundary
    float4 sv; sv.x = S0; sv.y = S1; sv.z = S2; sv.w = S3;
    *reinterpret_cast<float4*>(&hist[hb + 4 * lane]) = sv;
    __builtin_amdgcn_s_waitcnt(0);
    float Gl = hist[hb + binsel];
    float Gh = (binsel < 255) ? hist[hb + binsel + 1] : 0.0f;
    float sl = (binsel == 0) ? 0.0f            // bin0 holds clamped tinies too
             : __uint_as_float((unsigned)(binsel + BINBASE) << 20);
    float sh = (binsel < 255)
             ? __uint_as_float((unsigned)(binsel + 1 + BINBASE) << 20) : 1.0f;

    // ---- Phase B: compact band [sl, sh); probe-refine fallback on overflow ----
    int C = 0;
    for (int attempt = 0; attempt < 2; ++attempt) {
        C = 0;
        #pragma unroll
        for (int k = 0; k < KPT; ++k) {
            const bool band = (p[k] >= sl) && (p[k] < sh);
            const unsigned long long mk = __ballot(band);
            if (band) {
                const unsigned mlo = (unsigned)mk, mhi = (unsigned)(mk >> 32);
                const int within = __builtin_amdgcn_mbcnt_hi(
                                       mhi, __builtin_amdgcn_mbcnt_lo(mlo, 0));
                const int pos = C + within;
                if (pos < 256) scomp[hb + pos] = p[k];
            }
            C += (int)__popcll(mk);
        }
        if (C <= 256 || attempt) break;
        // rare: one-bin band too dense -> classic exact probes within the bin
        int Cl = MCOLS, Ch = 0;
        for (int it = 0; it < 10 && (Cl - Ch) > 256; ++it) {
            float s;
            if (it & 1) {
                s = 0.5f * (sl + sh);
            } else {
                const float den = fmaxf(Gl - Gh, 1e-30f);
                s = sl + (sh - sl) * ((Gl - target) / den);
            }
            if (!(s > sl && s < sh)) s = 0.5f * (sl + sh);
            if (!(s > sl && s < sh)) break;    // ulp-width bracket

            float m0 = 0.0f, m1 = 0.0f, m2 = 0.0f, m3 = 0.0f;
            int   c = 0;
            #pragma unroll
            for (int k = 0; k < KPT; k += 4) {
                const bool g0 = (p[k]     >= s);
                const bool g1 = (p[k + 1] >= s);
                const bool g2 = (p[k + 2] >= s);
                const bool g3 = (p[k + 3] >= s);
                m0 += g0 ? p[k]     : 0.0f; c += (int)__popcll(__ballot(g0));
                m1 += g1 ? p[k + 1] : 0.0f; c += (int)__popcll(__ballot(g1));
                m2 += g2 ? p[k + 2] : 0.0f; c += (int)__popcll(__ballot(g2));
                m3 += g3 ? p[k + 3] : 0.0f; c += (int)__popcll(__ballot(g3));
            }
            const float m = dppSum((m0 + m1) + (m2 + m3));
            if (m >= target) { sl = s; Gl = m; Cl = c; }
            else             { sh = s; Gh = m; Ch = c; }
        }
    }
    __builtin_amdgcn_s_waitcnt(0);             // drain ds_writes (same wave)
    float cp[4];
    bool  cv[4];
    #pragma unroll
    for (int q = 0; q < 4; ++q) {
        const int idx = q * 64 + lane;
        cv[q] = (idx < C) && (idx < 256);
        cp[q] = cv[q] ? scomp[hb + idx] : 0.0f;
    }

    float pstar, mb = 0.0f;
    int   cnt = 1;
    bool  haveTie;

    if (C > 256) {
        // fallback (rare): keep everything >= sl (off by boundary elems)
        pstar = (sl > 0.0f) ? __uint_as_float(__float_as_uint(sl) - 1u) : 0.0f;
        haveTie = false;
    } else {
        // ---- Phase C1: cheap fine probes on the compact set ----
        float lo_s = sl, hi_s = sh, lo_G = Gl, hi_G = Gh;
        int   lo_C = C,  hi_C = 0;       // offset base; only differences used
        for (int it = 0; it < 10 && (lo_C - hi_C) > 2; ++it) {
            float s;
            if (it & 1) {
                s = 0.5f * (lo_s + hi_s);
            } else {
                const float den = fmaxf(lo_G - hi_G, 1e-30f);
                s = lo_s + (hi_s - lo_s) * ((lo_G - target) / den);
            }
            if (!(s > lo_s && s < hi_s)) s = 0.5f * (lo_s + hi_s);
            if (!(s > lo_s && s < hi_s)) break;

            float m = 0.0f;
            int   c = 0;
            #pragma unroll
            for (int q = 0; q < 4; ++q) {
                const bool ge = cv[q] && (cp[q] >= s);
                m += ge ? cp[q] : 0.0f;
                c += (int)__popcll(__ballot(ge));
            }
            m = Gh + dppSum(m);
            if (m >= target) { lo_s = s; lo_G = m; lo_C = c; }
            else             { hi_s = s; hi_G = m; hi_C = c; }
        }

        // ---- Phase C2: exact distinct-value walk downward from hi_s ----
        float scur = hi_s, M = hi_G;
        bool ok = false;
        pstar = lo_s;
        for (int e = 0; e < 16; ++e) {
            float vl = 0.0f;
            #pragma unroll
            for (int q = 0; q < 4; ++q)
                vl = fmaxf(vl, (cv[q] && cp[q] < scur) ? cp[q] : 0.0f);
            const float v = dppMax(vl);
            if (!(v > 0.0f)) break;            // fp knife-edge; fallback
            int cvn = 0;
            #pragma unroll
            for (int q = 0; q < 4; ++q)
                cvn += (int)__popcll(__ballot(cv[q] && (cp[q] == v)));
            const float Mn = M + v * (float)cvn;  // exact: ties bit-identical
            if (Mn >= target) { pstar = v; mb = M; cnt = cvn; ok = true; break; }
            M = Mn; scur = v;
        }
        haveTie = ok;
        if (!ok) {
            pstar = (lo_s > 0.0f) ? __uint_as_float(__float_as_uint(lo_s) - 1u)
                                  : 0.0f;
        }
    }

    // ---- Phase D: spd = sum_{p > p*} p * (-log p), 4-chain (R14) ----
    float s0 = 0.0f, s1 = 0.0f, s2 = 0.0f, s3 = 0.0f;
    #pragma unroll
    for (int k = 0; k < KPT; k += 4) {
        const float t0 = (p[k]     > pstar) ? p[k]     : 1.0f;   // log(1)=0
        const float t1 = (p[k + 1] > pstar) ? p[k + 1] : 1.0f;
        const float t2 = (p[k + 2] > pstar) ? p[k + 2] : 1.0f;
        const float t3 = (p[k + 3] > pstar) ? p[k + 3] : 1.0f;
        s0 += t0 * (-__logf(t0));
        s1 += t1 * (-__logf(t1));
        s2 += t2 * (-__logf(t2));
        s3 += t3 * (-__logf(t3));
    }
    const float spd = dppSum((s0 + s1) + (s2 + s3));

    if (lane == 0) {
        float tie = 0.0f;
        if (haveTie) {
            const float R = (target - mb) / pstar;      // exclusive-csum rule
            int q = (int)ceilf(R);
            if (q < 1) q = 1;
            if (q > cnt) q = cnt;
            tie = (float)q * pstar * (-__logf(pstar));
        }
        wacc[wid] = (spd + tie) / Z;
    }
    __syncthreads();                     // all waves reach exactly once
    if (tid == 0) {
        const float v = wacc[0] + wacc[1] + wacc[2] + wacc[3];
        if (partial) partial[blockIdx.x] = v;   // no same-address atomic
        else         atomicAdd(out, v);         // ws_size fallback
    }
}

// Deterministic 2nd-stage reduce: nblocks (<=4096) floats -> out[0].
__global__ __launch_bounds__(1024) void apml_reduce(
        const float* __restrict__ partial, float* __restrict__ out, int n) {
    __shared__ float s[16];
    const int t = threadIdx.x;
    float a = 0.0f;
    #pragma unroll
    for (int q = 0; q < 4; ++q) {
        const int i = t * 4 + q;
        a += (i < n) ? partial[i] : 0.0f;
    }
    a = dppSum(a);
    if ((t & 63) == 0) s[t >> 6] = a;
    __syncthreads();
    if (t == 0) {
        float r = 0.0f;
        #pragma unroll
        for (int w = 0; w < 16; ++w) r += s[w];
        out[0] = r;
    }
}

extern "C" void kernel_launch(void* const* d_in, const int* in_sizes, int n_in,
                              void* d_out, int out_size, void* d_ws, size_t ws_size,
                              hipStream_t stream) {
    const float* x = (const float*)d_in[0];   // [B, N, 3]
    const float* y = (const float*)d_in[1];   // [B, M, 3]
    float* out = (float*)d_out;               // scalar

    const int nrows = in_sizes[0] / 3;        // B * N
    const int nblocks = nrows / WPB;          // 4096

    if (d_ws && ws_size >= (size_t)nblocks * sizeof(float) && nblocks <= 4096) {
        float* partial = (float*)d_ws;
        apml_row_wave<<<nblocks, WPB * 64, 0, stream>>>(x, y, partial, out);
        apml_reduce<<<1, 1024, 0, stream>>>(partial, out, nblocks);
    } else {
        hipMemsetAsync(out, 0, sizeof(float), stream);   // capture-legal
        apml_row_wave<<<nblocks, WPB * 64, 0, stream>>>(x, y, nullptr, out);
    }
}